// Round 7
// baseline (197.980 us; speedup 1.0000x reference)
//
#include <hip/hip_runtime.h>

#define C_   512
#define HW_  4096
#define NTOK 8192
#define PZ_  16777216L   // Pexp batch stride (elems) in big mode

typedef __attribute__((ext_vector_type(8))) short bf16x8;
typedef __attribute__((ext_vector_type(4))) float f32x4;
typedef unsigned short u16;

#define MFMA16 __builtin_amdgcn_mfma_f32_16x16x32_bf16

__device__ __forceinline__ u16 f2bf(float f) {
  unsigned int u = __float_as_uint(f);
  u += 0x7fffu + ((u >> 16) & 1u);
  return (u16)(u >> 16);
}

__device__ __forceinline__ float bf2f(u16 v) {
  return __uint_as_float((unsigned)v << 16);
}

__device__ __forceinline__ void gld_lds16(const u16* g, u16* l) {
  __builtin_amdgcn_global_load_lds(
      (const __attribute__((address_space(1))) void*)g,
      (__attribute__((address_space(3))) void*)l, 16, 0, 0);
}

// swizzled LDS chunk address: logical (row, u16-col) -> physical u16 offset.
// Layout: within each row (8 chunks of 16B), chunk o stored at o ^ (row&7).
// Paired with inverse-swizzled global source in the staging loop.
__device__ __forceinline__ const u16* swz(const u16* base, int row, int col, int ldu16) {
  return base + (size_t)row * ldu16 + ((((col >> 3) ^ (row & 7)) << 3) | (col & 7));
}

// ---------------- weight fp32 -> bf16 cast (4 matrices of 512x512) ----------
__global__ void wcast_kernel(const float* __restrict__ a, const float* __restrict__ b,
                             const float* __restrict__ c, const float* __restrict__ d,
                             u16* __restrict__ out) {
  int gid = blockIdx.x * 256 + threadIdx.x;   // 262144 threads, 4 floats each
  int which = gid >> 16;
  const float* src = which == 0 ? a : which == 1 ? b : which == 2 ? c : d;
  int loc = (gid & 65535) * 4;
  float4 v = *(const float4*)(src + loc);
  ushort4 o;
  o.x = f2bf(v.x); o.y = f2bf(v.y); o.z = f2bf(v.z); o.w = f2bf(v.w);
  *(ushort4*)(out + ((size_t)which << 18) + loc) = o;
}

// ---------------- GroupNorm stats: one block per (batch, group) -------------
__global__ __launch_bounds__(256) void gn_stats_kernel(const float* __restrict__ x,
                                                       float* __restrict__ gstat) {
  const int blk = blockIdx.x;  // b*32+g, slice is contiguous 65536 floats
  const float4* p = (const float4*)(x + (size_t)blk * 65536);
  float s = 0.0f, ss = 0.0f;
  for (int i = threadIdx.x; i < 16384; i += 256) {
    float4 v = p[i];
    s  += v.x + v.y + v.z + v.w;
    ss += v.x * v.x + v.y * v.y + v.z * v.z + v.w * v.w;
  }
  #pragma unroll
  for (int m = 1; m < 64; m <<= 1) { s += __shfl_xor(s, m); ss += __shfl_xor(ss, m); }
  __shared__ float rs[4], rss[4];
  const int wv = threadIdx.x >> 6;
  if ((threadIdx.x & 63) == 0) { rs[wv] = s; rss[wv] = ss; }
  __syncthreads();
  if (threadIdx.x == 0) {
    float S  = rs[0] + rs[1] + rs[2] + rs[3];
    float SS = rss[0] + rss[1] + rss[2] + rss[3];
    float mean = S * (1.0f / 65536.0f);
    float var  = fmaxf(SS * (1.0f / 65536.0f) - mean * mean, 0.0f);
    gstat[2 * blk]     = mean;
    gstat[2 * blk + 1] = rsqrtf(var + 1e-6f);
  }
}

// ---------------- GN apply + transpose to token-major bf16 hT[8192][512] ----
__global__ __launch_bounds__(256) void gn_apply_kernel(const float* __restrict__ x,
                                                       const float* __restrict__ gnw,
                                                       const float* __restrict__ gnb,
                                                       const float* __restrict__ gstat,
                                                       u16* __restrict__ hT) {
  const int b = blockIdx.z, c0 = blockIdx.y * 64, hw0 = blockIdx.x * 64;
  const int t = threadIdx.x;
  __shared__ float tile[64][65];
  {
    const int tx = t & 63, ty = t >> 6;  // ty 0..3
    #pragma unroll
    for (int i = 0; i < 16; ++i) {
      int cl = ty * 16 + i;
      int c = c0 + cl;
      int g = b * 32 + (c >> 4);
      float mean = gstat[2 * g], rstd = gstat[2 * g + 1];
      float val = x[((size_t)(b * C_ + c)) * HW_ + hw0 + tx];
      tile[cl][tx] = (val - mean) * rstd * gnw[c] + gnb[c];
    }
  }
  __syncthreads();
  {
    const int cx = (t & 31) * 2, ty = t >> 5;  // ty 0..7
    #pragma unroll
    for (int i = 0; i < 8; ++i) {
      int hwl = ty * 8 + i;
      unsigned pk = (unsigned)f2bf(tile[cx][hwl]) | ((unsigned)f2bf(tile[cx + 1][hwl]) << 16);
      *(unsigned*)&hT[((size_t)(b * HW_ + hw0 + hwl)) * C_ + c0 + cx] = pk;
    }
  }
}

// ---------------- generic bf16 A(MxK) @ B(NxK)^T GEMM, 64x64 tile -----------
// BIAS_N: bias indexed by n (else by m). RESID: fp32 out + residual add.
template<int BIAS_N, int RESID>
__global__ __launch_bounds__(256, 4) void gemm_abt(
    const u16* __restrict__ A, int lda,
    const u16* __restrict__ B, int ldb, long bz,
    const float* __restrict__ bias,
    const float* __restrict__ resid,
    void* __restrict__ Dp, int ldd, long dz, int K)
{
  B += (size_t)blockIdx.z * (size_t)bz;
  const int t = threadIdx.x;
  const int m0 = blockIdx.x * 64, n0 = blockIdx.y * 64;
  const int wv = t >> 6, l = t & 63, lr = l & 15, lq = l >> 4;
  const int ro = (wv >> 1) * 32, co = (wv & 1) * 32;
  __shared__ u16 As[64][72];
  __shared__ u16 Bs[64][72];
  f32x4 acc[2][2] = {};
  const int ldr_ = t >> 2;
  const int ldc_ = (t & 3) * 16;
  for (int k0 = 0; k0 < K; k0 += 64) {
    *(uint4*)&As[ldr_][ldc_]     = *(const uint4*)(A + (size_t)(m0 + ldr_) * lda + k0 + ldc_);
    *(uint4*)&As[ldr_][ldc_ + 8] = *(const uint4*)(A + (size_t)(m0 + ldr_) * lda + k0 + ldc_ + 8);
    *(uint4*)&Bs[ldr_][ldc_]     = *(const uint4*)(B + (size_t)(n0 + ldr_) * ldb + k0 + ldc_);
    *(uint4*)&Bs[ldr_][ldc_ + 8] = *(const uint4*)(B + (size_t)(n0 + ldr_) * ldb + k0 + ldc_ + 8);
    __syncthreads();
    #pragma unroll
    for (int kk = 0; kk < 64; kk += 32) {
      bf16x8 a0 = *(const bf16x8*)&As[ro + lr][kk + lq * 8];
      bf16x8 a1 = *(const bf16x8*)&As[ro + 16 + lr][kk + lq * 8];
      bf16x8 b0 = *(const bf16x8*)&Bs[co + lr][kk + lq * 8];
      bf16x8 b1 = *(const bf16x8*)&Bs[co + 16 + lr][kk + lq * 8];
      acc[0][0] = MFMA16(a0, b0, acc[0][0], 0, 0, 0);
      acc[0][1] = MFMA16(a0, b1, acc[0][1], 0, 0, 0);
      acc[1][0] = MFMA16(a1, b0, acc[1][0], 0, 0, 0);
      acc[1][1] = MFMA16(a1, b1, acc[1][1], 0, 0, 0);
    }
    __syncthreads();
  }
  #pragma unroll
  for (int rf = 0; rf < 2; ++rf) {
    #pragma unroll
    for (int cf = 0; cf < 2; ++cf) {
      const int n = n0 + co + cf * 16 + lr;
      const float bn = BIAS_N ? bias[n] : 0.0f;
      #pragma unroll
      for (int reg = 0; reg < 4; ++reg) {
        const int m = m0 + ro + rf * 16 + lq * 4 + reg;
        float val = acc[rf][cf][reg] + (BIAS_N ? bn : bias[m]);
        if (RESID) {
          float* D = (float*)Dp + (size_t)blockIdx.z * dz;
          const float* R = resid + (size_t)blockIdx.z * dz;
          size_t idx = (size_t)m * ldd + n;
          D[idx] = val + R[idx];
        } else {
          ((u16*)Dp)[(size_t)m * ldd + n] = f2bf(val);
        }
      }
    }
  }
}

// ---------------- S-GEMM 256x256 8-phase + exp + rowsum partials ------------
// z = batch. A=qm[z] [4096][512], B=km[z] [4096][512]. Tile 256x256, BK=64.
// 8 waves (2M x 4N), per-wave out 128x64. LDS 128KB double-buffered,
// XOR-swizzled. Per K-tile: 4 phases {ds_read || stage-quarter(next tile) ->
// barrier -> lgkmcnt(0) -> 16 MFMA} with one vmcnt(0) after phase-3 MFMAs.
__global__ __launch_bounds__(512, 1) void sgemm_exp_kernel(
    const u16* __restrict__ A, const u16* __restrict__ B,
    u16* __restrict__ Pexp, float* __restrict__ rsp, long pz, int gi0base)
{
  const int z = blockIdx.z;
  A    += (size_t)z * (HW_ * C_);
  B    += (size_t)z * (HW_ * C_);
  Pexp += (size_t)z * pz;
  const int gi0 = gi0base + z * HW_;
  const int t = threadIdx.x;
  const int m0 = blockIdx.x * 256, n0 = blockIdx.y * 256;
  const int wv = t >> 6, l = t & 63, lr = l & 15, lq = l >> 4;
  const int wr = wv >> 2, wc = wv & 3;     // 2M x 4N waves, wave tile 128x64
  __shared__ u16 As[2][16384];             // [256][64] swizzled, x2 buffers
  __shared__ u16 Bs[2][16384];
  f32x4 acc[8][4] = {};

  // prologue: stage tile 0 -> buf0 (8 gld_lds/thread), full drain
  #pragma unroll
  for (int p = 0; p < 4; ++p) {
    const int c = p * 512 + t, row = c >> 3, oct = (c & 7) ^ (row & 7);
    gld_lds16(A + (size_t)(m0 + row) * 512 + oct * 8, As[0] + c * 8);
    gld_lds16(B + (size_t)(n0 + row) * 512 + oct * 8, Bs[0] + c * 8);
  }
  __syncthreads();

  for (int kt = 0; kt < 8; ++kt) {
    const int cb = kt & 1, nb = cb ^ 1;
    const int k0n = (kt + 1) * 64;
    bf16x8 bfr[4][2];
    #pragma unroll
    for (int p = 0; p < 4; ++p) {
      // ---- ds_read this phase's fragments (B fully at p==0) ----
      if (p == 0) {
        #pragma unroll
        for (int fc = 0; fc < 4; ++fc)
          #pragma unroll
          for (int kh = 0; kh < 2; ++kh) {
            const int r = wc * 64 + fc * 16 + lr;
            bfr[fc][kh] = *(const bf16x8*)(Bs[cb] + r * 64 + ((((kh << 2) + lq) ^ (r & 7)) << 3));
          }
      }
      bf16x8 af[2][2];
      #pragma unroll
      for (int i = 0; i < 2; ++i)
        #pragma unroll
        for (int kh = 0; kh < 2; ++kh) {
          const int r = wr * 128 + (p * 2 + i) * 16 + lr;
          af[i][kh] = *(const bf16x8*)(As[cb] + r * 64 + ((((kh << 2) + lq) ^ (r & 7)) << 3));
        }
      // ---- stage quarter of next K-tile into the other buffer ----
      if (kt < 7) {
        const int c = p * 512 + t, row = c >> 3, oct = (c & 7) ^ (row & 7);
        gld_lds16(A + (size_t)(m0 + row) * 512 + k0n + oct * 8, As[nb] + c * 8);
        gld_lds16(B + (size_t)(n0 + row) * 512 + k0n + oct * 8, Bs[nb] + c * 8);
      }
      __builtin_amdgcn_s_barrier();
      asm volatile("s_waitcnt lgkmcnt(0)" ::: "memory");
      __builtin_amdgcn_sched_barrier(0);
      __builtin_amdgcn_s_setprio(1);
      #pragma unroll
      for (int i = 0; i < 2; ++i)
        #pragma unroll
        for (int fc = 0; fc < 4; ++fc)
          #pragma unroll
          for (int kh = 0; kh < 2; ++kh)
            acc[p * 2 + i][fc] = MFMA16(af[i][kh], bfr[fc][kh], acc[p * 2 + i][fc], 0, 0, 0);
      __builtin_amdgcn_s_setprio(0);
      if (p == 3) {
        asm volatile("s_waitcnt vmcnt(0)" ::: "memory");
        __builtin_amdgcn_sched_barrier(0);
      }
      __builtin_amdgcn_s_barrier();
    }
  }

  // epilogue: exp2(s*scale), rowsum partial over this wave's 64 cols, stores
  const float SCL2 = 0.06376774487989831f;   // log2(e)/sqrt(512)
  #pragma unroll
  for (int fr = 0; fr < 8; ++fr) {
    #pragma unroll
    for (int reg = 0; reg < 4; ++reg) {
      float rsum = 0.0f;
      const int row = m0 + wr * 128 + fr * 16 + lq * 4 + reg;
      u16* prow = Pexp + (size_t)row * 4096 + n0 + wc * 64 + lr;
      #pragma unroll
      for (int fc = 0; fc < 4; ++fc) {
        float p = exp2f(acc[fr][fc][reg] * SCL2);
        rsum += p;
        prow[fc * 16] = f2bf(p);
      }
      rsum += __shfl_xor(rsum, 1);
      rsum += __shfl_xor(rsum, 2);
      rsum += __shfl_xor(rsum, 4);
      rsum += __shfl_xor(rsum, 8);
      if (lr == 0)
        rsp[(size_t)(blockIdx.y * 4 + wc) * NTOK + gi0 + row] = rsum;
    }
  }
}

// ---------------- rowsum reduce: rinv[i] = 1/sum_j rsp[j][i] ----------------
__global__ __launch_bounds__(512) void rs_reduce_kernel(const float* __restrict__ rsp,
                                                        float* __restrict__ rinv, int gi0) {
  const int i = gi0 + blockIdx.x * 512 + threadIdx.x;
  float s = 0.0f;
  #pragma unroll 8
  for (int jg = 0; jg < 64; ++jg) s += rsp[(size_t)jg * NTOK + i];
  rinv[i] = 1.0f / s;
}

// ---------------- PV GEMM split-K: Op[sp] = Pexp @ V^T over K-half sp -------
// z encodes (split, batch): sp = z&1, b = z>>1. A=Pexp [4096][4096];
// B=vm channel-major rows [512][tok]. Tile 64x64, BK=64, K=2048 per split.
// LDS tiles XOR-swizzled (inverse-swizzled global src + swizzled ds_read).
__global__ __launch_bounds__(256, 8) void pvgemm_splitk(
    const u16* __restrict__ A, const u16* __restrict__ B,
    u16* __restrict__ Op0, u16* __restrict__ Op1)
{
  const int z = blockIdx.z;
  const int bb = z >> 1;
  A += (size_t)bb * PZ_;
  B += (size_t)bb * HW_;
  u16* Op = (z & 1) ? Op1 : Op0;
  Op += (size_t)bb * (HW_ * C_);
  const int t = threadIdx.x;
  const int m0 = blockIdx.x * 64, n0 = blockIdx.y * 64;
  const int wv = t >> 6, l = t & 63, lr = l & 15, lq = l >> 4;
  const int wr = wv >> 1, wc = wv & 1;       // 2x2 waves of 32x32
  __shared__ u16 As[64][64];
  __shared__ u16 Bs[64][64];
  f32x4 acc[2][2] = {};
  const int kbeg = (z & 1) * 2048;
  for (int k0 = kbeg; k0 < kbeg + 2048; k0 += 64) {
    #pragma unroll
    for (int it = 0; it < 2; ++it) {
      const int ci = it * 256 + t;           // 512 chunks of 16B per buffer
      const int row = ci >> 3;
      const int c8 = (((ci & 7) ^ (row & 7)) << 3);  // inverse-swizzled src octet
      gld_lds16(A + (size_t)(m0 + row) * 4096 + k0 + c8, &As[0][0] + ci * 8);
      gld_lds16(B + (size_t)(n0 + row) * NTOK + k0 + c8, &Bs[0][0] + ci * 8);
    }
    __syncthreads();
    #pragma unroll
    for (int kk = 0; kk < 64; kk += 32) {
      bf16x8 af[2], bf[2];
      #pragma unroll
      for (int fr = 0; fr < 2; ++fr)
        af[fr] = *(const bf16x8*)swz(&As[0][0], wr * 32 + fr * 16 + lr, kk + lq * 8, 64);
      #pragma unroll
      for (int fc = 0; fc < 2; ++fc)
        bf[fc] = *(const bf16x8*)swz(&Bs[0][0], wc * 32 + fc * 16 + lr, kk + lq * 8, 64);
      #pragma unroll
      for (int fr = 0; fr < 2; ++fr)
        #pragma unroll
        for (int fc = 0; fc < 2; ++fc)
          acc[fr][fc] = MFMA16(af[fr], bf[fc], acc[fr][fc], 0, 0, 0);
    }
    __syncthreads();
  }
  #pragma unroll
  for (int fr = 0; fr < 2; ++fr) {
    #pragma unroll
    for (int reg = 0; reg < 4; ++reg) {
      const int m = m0 + wr * 32 + fr * 16 + lq * 4 + reg;
      u16* orow = Op + (size_t)m * 512 + n0 + wc * 32 + lr;
      #pragma unroll
      for (int fc = 0; fc < 2; ++fc)
        orow[fc * 16] = f2bf(acc[fr][fc][reg]);
    }
  }
}

// ---------------- combine split-K partials, normalize by rinv, -> ao --------
__global__ __launch_bounds__(256) void combine_norm(const u16* __restrict__ Op0,
                                                    const u16* __restrict__ Op1,
                                                    const float* __restrict__ rinv,
                                                    u16* __restrict__ ao) {
  const size_t idx8 = ((size_t)blockIdx.x * 256 + threadIdx.x) * 8;
  const float ri = rinv[idx8 >> 9];
  ushort4 a0 = *(const ushort4*)(Op0 + idx8);
  ushort4 a1 = *(const ushort4*)(Op0 + idx8 + 4);
  ushort4 b0 = *(const ushort4*)(Op1 + idx8);
  ushort4 b1 = *(const ushort4*)(Op1 + idx8 + 4);
  ushort4 o0, o1;
  o0.x = f2bf((bf2f(a0.x) + bf2f(b0.x)) * ri);
  o0.y = f2bf((bf2f(a0.y) + bf2f(b0.y)) * ri);
  o0.z = f2bf((bf2f(a0.z) + bf2f(b0.z)) * ri);
  o0.w = f2bf((bf2f(a0.w) + bf2f(b0.w)) * ri);
  o1.x = f2bf((bf2f(a1.x) + bf2f(b1.x)) * ri);
  o1.y = f2bf((bf2f(a1.y) + bf2f(b1.y)) * ri);
  o1.z = f2bf((bf2f(a1.z) + bf2f(b1.z)) * ri);
  o1.w = f2bf((bf2f(a1.w) + bf2f(b1.w)) * ri);
  *(ushort4*)(ao + idx8)     = o0;
  *(ushort4*)(ao + idx8 + 4) = o1;
}

extern "C" void kernel_launch(void* const* d_in, const int* in_sizes, int n_in,
                              void* d_out, int out_size, void* d_ws, size_t ws_size,
                              hipStream_t stream) {
  const float* x   = (const float*)d_in[0];
  const float* gnw = (const float*)d_in[1];
  const float* gnb = (const float*)d_in[2];
  const float* qw  = (const float*)d_in[3];
  const float* qb  = (const float*)d_in[4];
  const float* kw  = (const float*)d_in[5];
  const float* kb  = (const float*)d_in[6];
  const float* vw  = (const float*)d_in[7];
  const float* vb  = (const float*)d_in[8];
  const float* pw  = (const float*)d_in[9];
  const float* pb  = (const float*)d_in[10];

  // common prefix layout (both modes)
  char* ws = (char*)d_ws;
  u16*   wqb   = (u16*)(ws + 0);             // 4x 512x512 bf16 (2MB)
  u16*   wkb   = wqb + 262144;
  u16*   wvb   = wkb + 262144;
  u16*   wpb   = wvb + 262144;
  float* gstat = (float*)(ws + 2097152);     // 64 x (mean, rstd)
  float* rinv  = (float*)(ws + 2097664);     // [8192] f32
  float* rsp   = (float*)(ws + 2130432);     // [64][8192] f32 (2MB)
  u16*   hT    = (u16*)(ws + 4227584);       // [8192][512] bf16 (8MB), dead after v-GEMM
  u16*   ao    = hT;                         // reuses hT region: [2][4096][512] bf16
  u16*   qm    = (u16*)(ws + 12616192);      // [8192][512] bf16
  u16*   km    = (u16*)(ws + 21004800);      // [8192][512] bf16
  u16*   vm    = (u16*)(ws + 29393408);      // [512][8192] bf16

  // big mode (ws >= ~122MB): both-batch Pexp + separate Op partials
  const bool big = ws_size >= 121668096ULL;
  u16* Op0B  = (u16*)(ws + 37782016);        // [2][4096][512] bf16 (8MB)
  u16* Op1B  = (u16*)(ws + 46170624);        // [2][4096][512] bf16 (8MB)
  u16* PexpB = (u16*)(ws + 54559232);        // [2][4096][4096] bf16 (67MB)
  // fallback (ws >= 77.66MB proven): single-batch Pexp, Op aliases qm/km
  u16* PexpS = (u16*)(ws + 37782016);        // [4096][4096] bf16 (33.5MB)

  wcast_kernel<<<1024, 256, 0, stream>>>(qw, kw, vw, pw, wqb);
  gn_stats_kernel<<<64, 256, 0, stream>>>(x, gstat);
  gn_apply_kernel<<<dim3(64, 8, 2), 256, 0, stream>>>(x, gnw, gnb, gstat, hT);
  // q, k: token-major, bias per-n
  gemm_abt<1, 0><<<dim3(128, 8), 256, 0, stream>>>(hT, 512, wqb, 512, 0, qb, nullptr, qm, 512, 0, 512);
  gemm_abt<1, 0><<<dim3(128, 8), 256, 0, stream>>>(hT, 512, wkb, 512, 0, kb, nullptr, km, 512, 0, 512);
  // v: channel-major, bias per-m
  gemm_abt<0, 0><<<dim3(8, 128), 256, 0, stream>>>(wvb, 512, hT, 512, 0, vb, nullptr, vm, 8192, 0, 512);

  if (big) {
    sgemm_exp_kernel<<<dim3(16, 16, 2), 512, 0, stream>>>(qm, km, PexpB, rsp, PZ_, 0);
    rs_reduce_kernel<<<16, 512, 0, stream>>>(rsp, rinv, 0);
    pvgemm_splitk<<<dim3(64, 8, 4), 256, 0, stream>>>(PexpB, vm, Op0B, Op1B);
    combine_norm<<<2048, 256, 0, stream>>>(Op0B, Op1B, rinv, ao);
  } else {
    u16* Op0 = qm;   // qm/km slices dead once pvgemm runs
    u16* Op1 = km;
    for (int b = 0; b < 2; ++b) {
      const u16* qmb = qm + (size_t)b * HW_ * C_;
      const u16* kmb = km + (size_t)b * HW_ * C_;
      sgemm_exp_kernel<<<dim3(16, 16, 1), 512, 0, stream>>>(qmb, kmb, PexpS, rsp, 0L, b * HW_);
      rs_reduce_kernel<<<8, 512, 0, stream>>>(rsp, rinv, b * HW_);
      pvgemm_splitk<<<dim3(64, 8, 2), 256, 0, stream>>>(PexpS, vm + (size_t)b * HW_, Op0, Op1);
      combine_norm<<<1024, 256, 0, stream>>>(Op0, Op1, rinv + b * HW_, ao + (size_t)b * HW_ * C_);
    }
  }
  // proj + bias + residual, fp32 out, per-batch via blockIdx.z
  gemm_abt<0, 1><<<dim3(8, 64, 2), 256, 0, stream>>>(wpb, 512, ao, 512, 2097152L, pb, x, d_out, 4096, 2097152L, 512);
}

// Round 8
// 173.143 us; speedup vs baseline: 1.1435x; 1.1435x over previous
//
#include <hip/hip_runtime.h>

#define C_   512
#define HW_  4096
#define NTOK 8192
#define PZ_  16777216L   // Pexp batch stride (elems) in big mode

typedef __attribute__((ext_vector_type(8))) short bf16x8;
typedef __attribute__((ext_vector_type(4))) float f32x4;
typedef unsigned short u16;

#define MFMA16 __builtin_amdgcn_mfma_f32_16x16x32_bf16

__device__ __forceinline__ u16 f2bf(float f) {
  unsigned int u = __float_as_uint(f);
  u += 0x7fffu + ((u >> 16) & 1u);
  return (u16)(u >> 16);
}

__device__ __forceinline__ float bf2f(u16 v) {
  return __uint_as_float((unsigned)v << 16);
}

__device__ __forceinline__ void gld_lds16(const u16* g, u16* l) {
  __builtin_amdgcn_global_load_lds(
      (const __attribute__((address_space(1))) void*)g,
      (__attribute__((address_space(3))) void*)l, 16, 0, 0);
}

// swizzled LDS chunk address: logical (row, u16-col) -> physical u16 offset.
// Layout: within each row (8 chunks of 16B), chunk o stored at o ^ (row&7).
// Paired with inverse-swizzled global source in the staging loop.
__device__ __forceinline__ const u16* swz(const u16* base, int row, int col, int ldu16) {
  return base + (size_t)row * ldu16 + ((((col >> 3) ^ (row & 7)) << 3) | (col & 7));
}

// ---------------- weight fp32 -> bf16 cast (4 matrices of 512x512) ----------
__global__ void wcast_kernel(const float* __restrict__ a, const float* __restrict__ b,
                             const float* __restrict__ c, const float* __restrict__ d,
                             u16* __restrict__ out) {
  int gid = blockIdx.x * 256 + threadIdx.x;   // 262144 threads, 4 floats each
  int which = gid >> 16;
  const float* src = which == 0 ? a : which == 1 ? b : which == 2 ? c : d;
  int loc = (gid & 65535) * 4;
  float4 v = *(const float4*)(src + loc);
  ushort4 o;
  o.x = f2bf(v.x); o.y = f2bf(v.y); o.z = f2bf(v.z); o.w = f2bf(v.w);
  *(ushort4*)(out + ((size_t)which << 18) + loc) = o;
}

// ---------------- GroupNorm stats, two-stage ------------------------------
// stage1: grid (64 groups, 8 chunks) -> partial (s, ss) per (group, chunk)
__global__ __launch_bounds__(256) void gn_stats1_kernel(const float* __restrict__ x,
                                                        float* __restrict__ gpart) {
  const float4* p = (const float4*)(x + (size_t)blockIdx.x * 65536 + blockIdx.y * 8192);
  float s = 0.0f, ss = 0.0f;
  for (int i = threadIdx.x; i < 2048; i += 256) {
    float4 v = p[i];
    s  += v.x + v.y + v.z + v.w;
    ss += v.x * v.x + v.y * v.y + v.z * v.z + v.w * v.w;
  }
  #pragma unroll
  for (int m = 1; m < 64; m <<= 1) { s += __shfl_xor(s, m); ss += __shfl_xor(ss, m); }
  __shared__ float rs[4], rss[4];
  const int wv = threadIdx.x >> 6;
  if ((threadIdx.x & 63) == 0) { rs[wv] = s; rss[wv] = ss; }
  __syncthreads();
  if (threadIdx.x == 0) {
    gpart[(blockIdx.x * 8 + blockIdx.y) * 2]     = rs[0] + rs[1] + rs[2] + rs[3];
    gpart[(blockIdx.x * 8 + blockIdx.y) * 2 + 1] = rss[0] + rss[1] + rss[2] + rss[3];
  }
}

// stage2: 64 threads, one group each
__global__ void gn_stats2_kernel(const float* __restrict__ gpart,
                                 float* __restrict__ gstat) {
  const int g = threadIdx.x;
  float s = 0.0f, ss = 0.0f;
  #pragma unroll
  for (int c = 0; c < 8; ++c) {
    s  += gpart[(g * 8 + c) * 2];
    ss += gpart[(g * 8 + c) * 2 + 1];
  }
  float mean = s * (1.0f / 65536.0f);
  float var  = fmaxf(ss * (1.0f / 65536.0f) - mean * mean, 0.0f);
  gstat[2 * g]     = mean;
  gstat[2 * g + 1] = rsqrtf(var + 1e-6f);
}

// ---------------- GN apply + transpose to token-major bf16 hT[8192][512] ----
__global__ __launch_bounds__(256) void gn_apply_kernel(const float* __restrict__ x,
                                                       const float* __restrict__ gnw,
                                                       const float* __restrict__ gnb,
                                                       const float* __restrict__ gstat,
                                                       u16* __restrict__ hT) {
  const int b = blockIdx.z, c0 = blockIdx.y * 64, hw0 = blockIdx.x * 64;
  const int t = threadIdx.x;
  __shared__ float tile[64][65];
  {
    const int tx = t & 63, ty = t >> 6;  // ty 0..3
    #pragma unroll
    for (int i = 0; i < 16; ++i) {
      int cl = ty * 16 + i;
      int c = c0 + cl;
      int g = b * 32 + (c >> 4);
      float mean = gstat[2 * g], rstd = gstat[2 * g + 1];
      float val = x[((size_t)(b * C_ + c)) * HW_ + hw0 + tx];
      tile[cl][tx] = (val - mean) * rstd * gnw[c] + gnb[c];
    }
  }
  __syncthreads();
  {
    const int cx = (t & 31) * 2, ty = t >> 5;  // ty 0..7
    #pragma unroll
    for (int i = 0; i < 8; ++i) {
      int hwl = ty * 8 + i;
      unsigned pk = (unsigned)f2bf(tile[cx][hwl]) | ((unsigned)f2bf(tile[cx + 1][hwl]) << 16);
      *(unsigned*)&hT[((size_t)(b * HW_ + hw0 + hwl)) * C_ + c0 + cx] = pk;
    }
  }
}

// ---------------- generic bf16 A(MxK) @ B(NxK)^T GEMM, 64x64 tile -----------
// BIAS_N: bias indexed by n (else by m). RESID: fp32 out + residual add.
template<int BIAS_N, int RESID>
__global__ __launch_bounds__(256, 4) void gemm_abt(
    const u16* __restrict__ A, int lda,
    const u16* __restrict__ B, int ldb, long bz,
    const float* __restrict__ bias,
    const float* __restrict__ resid,
    void* __restrict__ Dp, int ldd, long dz, int K)
{
  B += (size_t)blockIdx.z * (size_t)bz;
  const int t = threadIdx.x;
  const int m0 = blockIdx.x * 64, n0 = blockIdx.y * 64;
  const int wv = t >> 6, l = t & 63, lr = l & 15, lq = l >> 4;
  const int ro = (wv >> 1) * 32, co = (wv & 1) * 32;
  __shared__ u16 As[64][72];
  __shared__ u16 Bs[64][72];
  f32x4 acc[2][2] = {};
  const int ldr_ = t >> 2;
  const int ldc_ = (t & 3) * 16;
  for (int k0 = 0; k0 < K; k0 += 64) {
    *(uint4*)&As[ldr_][ldc_]     = *(const uint4*)(A + (size_t)(m0 + ldr_) * lda + k0 + ldc_);
    *(uint4*)&As[ldr_][ldc_ + 8] = *(const uint4*)(A + (size_t)(m0 + ldr_) * lda + k0 + ldc_ + 8);
    *(uint4*)&Bs[ldr_][ldc_]     = *(const uint4*)(B + (size_t)(n0 + ldr_) * ldb + k0 + ldc_);
    *(uint4*)&Bs[ldr_][ldc_ + 8] = *(const uint4*)(B + (size_t)(n0 + ldr_) * ldb + k0 + ldc_ + 8);
    __syncthreads();
    #pragma unroll
    for (int kk = 0; kk < 64; kk += 32) {
      bf16x8 a0 = *(const bf16x8*)&As[ro + lr][kk + lq * 8];
      bf16x8 a1 = *(const bf16x8*)&As[ro + 16 + lr][kk + lq * 8];
      bf16x8 b0 = *(const bf16x8*)&Bs[co + lr][kk + lq * 8];
      bf16x8 b1 = *(const bf16x8*)&Bs[co + 16 + lr][kk + lq * 8];
      acc[0][0] = MFMA16(a0, b0, acc[0][0], 0, 0, 0);
      acc[0][1] = MFMA16(a0, b1, acc[0][1], 0, 0, 0);
      acc[1][0] = MFMA16(a1, b0, acc[1][0], 0, 0, 0);
      acc[1][1] = MFMA16(a1, b1, acc[1][1], 0, 0, 0);
    }
    __syncthreads();
  }
  #pragma unroll
  for (int rf = 0; rf < 2; ++rf) {
    #pragma unroll
    for (int cf = 0; cf < 2; ++cf) {
      const int n = n0 + co + cf * 16 + lr;
      const float bn = BIAS_N ? bias[n] : 0.0f;
      #pragma unroll
      for (int reg = 0; reg < 4; ++reg) {
        const int m = m0 + ro + rf * 16 + lq * 4 + reg;
        float val = acc[rf][cf][reg] + (BIAS_N ? bn : bias[m]);
        if (RESID) {
          float* D = (float*)Dp + (size_t)blockIdx.z * dz;
          const float* R = resid + (size_t)blockIdx.z * dz;
          size_t idx = (size_t)m * ldd + n;
          D[idx] = val + R[idx];
        } else {
          ((u16*)Dp)[(size_t)m * ldd + n] = f2bf(val);
        }
      }
    }
  }
}

// ---------------- S-GEMM + exp + rowsum partials (m97 structure) ------------
// z = batch (big) or 0 (fallback; host pre-offsets). Tile 128x128, BK=64.
// LDS tiles XOR-swizzled (inverse-swizzled global src + swizzled ds_read).
__global__ __launch_bounds__(256, 2) void sgemm_exp_kernel(
    const u16* __restrict__ A, const u16* __restrict__ B,
    u16* __restrict__ Pexp, float* __restrict__ rsp, long pz, int gi0base)
{
  const int z = blockIdx.z;
  A    += (size_t)z * (HW_ * C_);
  B    += (size_t)z * (HW_ * C_);
  Pexp += (size_t)z * pz;
  const int gi0 = gi0base + z * HW_;
  const int t = threadIdx.x;
  const int m0 = blockIdx.x * 128, n0 = blockIdx.y * 128;
  const int wv = t >> 6, l = t & 63, lr = l & 15, lq = l >> 4;
  const int wr = wv >> 1, wc = wv & 1;       // 2x2 waves of 64x64
  __shared__ u16 As[128][64];
  __shared__ u16 Bs[128][64];
  f32x4 acc[4][4] = {};
  for (int k0 = 0; k0 < 512; k0 += 64) {
    #pragma unroll
    for (int it = 0; it < 4; ++it) {
      const int ci = it * 256 + t;           // 1024 chunks of 16B
      const int row = ci >> 3;
      const int c8 = (((ci & 7) ^ (row & 7)) << 3);  // inverse-swizzled src octet
      gld_lds16(A + (size_t)(m0 + row) * 512 + k0 + c8, &As[0][0] + ci * 8);
      gld_lds16(B + (size_t)(n0 + row) * 512 + k0 + c8, &Bs[0][0] + ci * 8);
    }
    __syncthreads();
    #pragma unroll
    for (int kk = 0; kk < 64; kk += 32) {
      bf16x8 af[4], bf[4];
      #pragma unroll
      for (int fr = 0; fr < 4; ++fr)
        af[fr] = *(const bf16x8*)swz(&As[0][0], wr * 64 + fr * 16 + lr, kk + lq * 8, 64);
      #pragma unroll
      for (int fc = 0; fc < 4; ++fc)
        bf[fc] = *(const bf16x8*)swz(&Bs[0][0], wc * 64 + fc * 16 + lr, kk + lq * 8, 64);
      #pragma unroll
      for (int fr = 0; fr < 4; ++fr)
        #pragma unroll
        for (int fc = 0; fc < 4; ++fc)
          acc[fr][fc] = MFMA16(af[fr], bf[fc], acc[fr][fc], 0, 0, 0);
    }
    __syncthreads();
  }
  // epilogue: exp2(s*scale), rowsum partial over this wave's 64 cols, stores
  const float SCL2 = 0.06376774487989831f;   // log2(e)/sqrt(512)
  #pragma unroll
  for (int fr = 0; fr < 4; ++fr) {
    #pragma unroll
    for (int reg = 0; reg < 4; ++reg) {
      float rsum = 0.0f;
      const int row = m0 + wr * 64 + fr * 16 + lq * 4 + reg;
      u16* prow = Pexp + (size_t)row * 4096 + n0 + wc * 64 + lr;
      #pragma unroll
      for (int fc = 0; fc < 4; ++fc) {
        float p = exp2f(acc[fr][fc][reg] * SCL2);
        rsum += p;
        prow[fc * 16] = f2bf(p);
      }
      rsum += __shfl_xor(rsum, 1);
      rsum += __shfl_xor(rsum, 2);
      rsum += __shfl_xor(rsum, 4);
      rsum += __shfl_xor(rsum, 8);
      if (lr == 0)
        rsp[(size_t)(blockIdx.y * 2 + wc) * NTOK + gi0 + row] = rsum;
    }
  }
}

// ---------------- rowsum reduce: rinv[i] = 1/sum_j rsp[j][i] ----------------
__global__ __launch_bounds__(512) void rs_reduce_kernel(const float* __restrict__ rsp,
                                                        float* __restrict__ rinv, int gi0) {
  const int i = gi0 + blockIdx.x * 512 + threadIdx.x;
  float s = 0.0f;
  #pragma unroll 8
  for (int jg = 0; jg < 64; ++jg) s += rsp[(size_t)jg * NTOK + i];
  rinv[i] = 1.0f / s;
}

// ---------------- PV GEMM split-K, 128x128 tile (m97 2:1 MFMA:ds ratio) -----
// z encodes (split, batch): sp = z & (nsplit-1), bb = z >> logsplit.
// A=Pexp [4096][4096]; B=vm channel-major rows [512][tok]. BK=64.
// Op layout: split stride 4194304 elems, batch stride 2097152 elems.
// LDS tiles XOR-swizzled (inverse-swizzled global src + swizzled ds_read).
__global__ __launch_bounds__(256, 4) void pvgemm_splitk(
    const u16* __restrict__ A, const u16* __restrict__ B,
    u16* __restrict__ Op, int logsplit)
{
  const int z = blockIdx.z;
  const int sp = z & ((1 << logsplit) - 1);
  const int bb = z >> logsplit;
  A  += (size_t)bb * PZ_;
  B  += (size_t)bb * HW_;
  Op += (size_t)sp * 4194304 + (size_t)bb * 2097152;
  const int t = threadIdx.x;
  const int m0 = blockIdx.x * 128, n0 = blockIdx.y * 128;
  const int wv = t >> 6, l = t & 63, lr = l & 15, lq = l >> 4;
  const int wr = wv >> 1, wc = wv & 1;       // 2x2 waves of 64x64
  __shared__ u16 As[128][64];
  __shared__ u16 Bs[128][64];
  f32x4 acc[4][4] = {};
  const int ksize = 4096 >> logsplit;
  const int kbeg = sp * ksize;
  for (int k0 = kbeg; k0 < kbeg + ksize; k0 += 64) {
    #pragma unroll
    for (int it = 0; it < 4; ++it) {
      const int ci = it * 256 + t;           // 1024 chunks of 16B per buffer
      const int row = ci >> 3;
      const int c8 = (((ci & 7) ^ (row & 7)) << 3);  // inverse-swizzled src octet
      gld_lds16(A + (size_t)(m0 + row) * 4096 + k0 + c8, &As[0][0] + ci * 8);
      gld_lds16(B + (size_t)(n0 + row) * NTOK + k0 + c8, &Bs[0][0] + ci * 8);
    }
    __syncthreads();
    #pragma unroll
    for (int kk = 0; kk < 64; kk += 32) {
      bf16x8 af[4], bf[4];
      #pragma unroll
      for (int fr = 0; fr < 4; ++fr)
        af[fr] = *(const bf16x8*)swz(&As[0][0], wr * 64 + fr * 16 + lr, kk + lq * 8, 64);
      #pragma unroll
      for (int fc = 0; fc < 4; ++fc)
        bf[fc] = *(const bf16x8*)swz(&Bs[0][0], wc * 64 + fc * 16 + lr, kk + lq * 8, 64);
      #pragma unroll
      for (int fr = 0; fr < 4; ++fr)
        #pragma unroll
        for (int fc = 0; fc < 4; ++fc)
          acc[fr][fc] = MFMA16(af[fr], bf[fc], acc[fr][fc], 0, 0, 0);
    }
    __syncthreads();
  }
  #pragma unroll
  for (int fr = 0; fr < 4; ++fr) {
    #pragma unroll
    for (int reg = 0; reg < 4; ++reg) {
      const int m = m0 + wr * 64 + fr * 16 + lq * 4 + reg;
      u16* orow = Op + (size_t)m * 512 + n0 + wc * 64 + lr;
      #pragma unroll
      for (int fc = 0; fc < 4; ++fc)
        orow[fc * 16] = f2bf(acc[fr][fc][reg]);
    }
  }
}

// ---------------- combine n split-K partials, normalize by rinv, -> ao ------
__global__ __launch_bounds__(256) void combine_norm(const u16* __restrict__ Op,
                                                    const float* __restrict__ rinv,
                                                    u16* __restrict__ ao, int nsplit) {
  const size_t idx8 = ((size_t)blockIdx.x * 256 + threadIdx.x) * 8;
  const float ri = rinv[idx8 >> 9];
  float v[8] = {};
  for (int s = 0; s < nsplit; ++s) {
    const u16* p = Op + (size_t)s * 4194304 + idx8;
    ushort4 a0 = *(const ushort4*)p;
    ushort4 a1 = *(const ushort4*)(p + 4);
    v[0] += bf2f(a0.x); v[1] += bf2f(a0.y); v[2] += bf2f(a0.z); v[3] += bf2f(a0.w);
    v[4] += bf2f(a1.x); v[5] += bf2f(a1.y); v[6] += bf2f(a1.z); v[7] += bf2f(a1.w);
  }
  ushort4 o0, o1;
  o0.x = f2bf(v[0] * ri); o0.y = f2bf(v[1] * ri);
  o0.z = f2bf(v[2] * ri); o0.w = f2bf(v[3] * ri);
  o1.x = f2bf(v[4] * ri); o1.y = f2bf(v[5] * ri);
  o1.z = f2bf(v[6] * ri); o1.w = f2bf(v[7] * ri);
  *(ushort4*)(ao + idx8)     = o0;
  *(ushort4*)(ao + idx8 + 4) = o1;
}

extern "C" void kernel_launch(void* const* d_in, const int* in_sizes, int n_in,
                              void* d_out, int out_size, void* d_ws, size_t ws_size,
                              hipStream_t stream) {
  const float* x   = (const float*)d_in[0];
  const float* gnw = (const float*)d_in[1];
  const float* gnb = (const float*)d_in[2];
  const float* qw  = (const float*)d_in[3];
  const float* qb  = (const float*)d_in[4];
  const float* kw  = (const float*)d_in[5];
  const float* kb  = (const float*)d_in[6];
  const float* vw  = (const float*)d_in[7];
  const float* vb  = (const float*)d_in[8];
  const float* pw  = (const float*)d_in[9];
  const float* pb  = (const float*)d_in[10];

  // common prefix layout (both modes)
  char* ws = (char*)d_ws;
  u16*   wqb   = (u16*)(ws + 0);             // 4x 512x512 bf16 (2MB)
  u16*   wkb   = wqb + 262144;
  u16*   wvb   = wkb + 262144;
  u16*   wpb   = wvb + 262144;
  float* gstat = (float*)(ws + 2097152);     // 64 x (mean, rstd)
  float* rinv  = (float*)(ws + 2097664);     // [8192] f32
  float* rsp   = (float*)(ws + 2130432);     // [64][8192] f32 (2MB)
  float* gpart = rsp;                        // gn partials alias rsp (pre-sgemm)
  u16*   hT    = (u16*)(ws + 4227584);       // [8192][512] bf16 (8MB), dead after v-GEMM
  u16*   ao    = hT;                         // reuses hT region: [2][4096][512] bf16
  u16*   qm    = (u16*)(ws + 12616192);      // [8192][512] bf16
  u16*   km    = (u16*)(ws + 21004800);      // [8192][512] bf16 (km-qm = 4194304 elems)
  u16*   vm    = (u16*)(ws + 29393408);      // [512][8192] bf16

  // big mode (ws >= ~138.5MB): both-batch Pexp + 4-way split-K Op partials
  const bool big = ws_size >= 138445312ULL;
  u16* OpB   = (u16*)(ws + 37782016);        // [4][2][4096][512] bf16 (33.5MB)
  u16* PexpB = (u16*)(ws + 71336448);        // [2][4096][4096] bf16 (67MB)
  // fallback (ws >= 77.66MB proven): single-batch Pexp, Op strided over qm/km
  u16* PexpS = (u16*)(ws + 37782016);        // [4096][4096] bf16 (33.5MB)

  wcast_kernel<<<1024, 256, 0, stream>>>(qw, kw, vw, pw, wqb);
  gn_stats1_kernel<<<dim3(64, 8), 256, 0, stream>>>(x, gpart);
  gn_stats2_kernel<<<1, 64, 0, stream>>>(gpart, gstat);
  gn_apply_kernel<<<dim3(64, 8, 2), 256, 0, stream>>>(x, gnw, gnb, gstat, hT);
  // q, k: token-major, bias per-n
  gemm_abt<1, 0><<<dim3(128, 8), 256, 0, stream>>>(hT, 512, wqb, 512, 0, qb, nullptr, qm, 512, 0, 512);
  gemm_abt<1, 0><<<dim3(128, 8), 256, 0, stream>>>(hT, 512, wkb, 512, 0, kb, nullptr, km, 512, 0, 512);
  // v: channel-major, bias per-m
  gemm_abt<0, 0><<<dim3(8, 128), 256, 0, stream>>>(wvb, 512, hT, 512, 0, vb, nullptr, vm, 8192, 0, 512);

  if (big) {
    sgemm_exp_kernel<<<dim3(32, 32, 2), 256, 0, stream>>>(qm, km, PexpB, rsp, PZ_, 0);
    rs_reduce_kernel<<<16, 512, 0, stream>>>(rsp, rinv, 0);
    pvgemm_splitk<<<dim3(32, 4, 8), 256, 0, stream>>>(PexpB, vm, OpB, 2);
    combine_norm<<<2048, 256, 0, stream>>>(OpB, rinv, ao, 4);
  } else {
    for (int b = 0; b < 2; ++b) {
      const u16* qmb = qm + (size_t)b * HW_ * C_;
      const u16* kmb = km + (size_t)b * HW_ * C_;
      sgemm_exp_kernel<<<dim3(32, 32, 1), 256, 0, stream>>>(qmb, kmb, PexpS, rsp, 0L, b * HW_);
      rs_reduce_kernel<<<8, 512, 0, stream>>>(rsp, rinv, b * HW_);
      // Op strided over qm/km dead b0 slices: qm + s*4194304 = {qm, km}
      pvgemm_splitk<<<dim3(32, 4, 2), 256, 0, stream>>>(PexpS, vm + (size_t)b * HW_, qm, 1);
      combine_norm<<<1024, 256, 0, stream>>>(qm, rinv + b * HW_, ao + (size_t)b * HW_ * C_, 2);
    }
  }
  // proj + bias + residual, fp32 out, per-batch via blockIdx.z
  gemm_abt<0, 1><<<dim3(8, 64, 2), 256, 0, stream>>>(wpb, 512, ao, 512, 2097152L, pb, x, d_out, 4096, 2097152L, 512);
}

// Round 9
// 161.457 us; speedup vs baseline: 1.2262x; 1.0724x over previous
//
#include <hip/hip_runtime.h>

#define C_   512
#define HW_  4096
#define NTOK 8192
#define PZ_  16777216L   // Pexp batch stride (elems) in big mode

typedef __attribute__((ext_vector_type(8))) short bf16x8;
typedef __attribute__((ext_vector_type(4))) float f32x4;
typedef unsigned short u16;

#define MFMA16 __builtin_amdgcn_mfma_f32_16x16x32_bf16

__device__ __forceinline__ u16 f2bf(float f) {
  unsigned int u = __float_as_uint(f);
  u += 0x7fffu + ((u >> 16) & 1u);
  return (u16)(u >> 16);
}

__device__ __forceinline__ float bf2f(u16 v) {
  return __uint_as_float((unsigned)v << 16);
}

__device__ __forceinline__ void gld_lds16(const u16* g, u16* l) {
  __builtin_amdgcn_global_load_lds(
      (const __attribute__((address_space(1))) void*)g,
      (__attribute__((address_space(3))) void*)l, 16, 0, 0);
}

// swizzled LDS chunk address: logical (row, u16-col) -> physical u16 offset.
// Layout: within each row (8 chunks of 16B), chunk o stored at o ^ (row&7).
// Paired with inverse-swizzled global source in the staging loop.
__device__ __forceinline__ const u16* swz(const u16* base, int row, int col, int ldu16) {
  return base + (size_t)row * ldu16 + ((((col >> 3) ^ (row & 7)) << 3) | (col & 7));
}

// ---------------- weight fp32 -> bf16 cast (4 matrices of 512x512) ----------
__global__ void wcast_kernel(const float* __restrict__ a, const float* __restrict__ b,
                             const float* __restrict__ c, const float* __restrict__ d,
                             u16* __restrict__ out) {
  int gid = blockIdx.x * 256 + threadIdx.x;   // 262144 threads, 4 floats each
  int which = gid >> 16;
  const float* src = which == 0 ? a : which == 1 ? b : which == 2 ? c : d;
  int loc = (gid & 65535) * 4;
  float4 v = *(const float4*)(src + loc);
  ushort4 o;
  o.x = f2bf(v.x); o.y = f2bf(v.y); o.z = f2bf(v.z); o.w = f2bf(v.w);
  *(ushort4*)(out + ((size_t)which << 18) + loc) = o;
}

// ---------------- GroupNorm stats stage1: (group, chunk) partials -----------
__global__ __launch_bounds__(256) void gn_stats1_kernel(const float* __restrict__ x,
                                                        float* __restrict__ gpart) {
  const float4* p = (const float4*)(x + (size_t)blockIdx.x * 65536 + blockIdx.y * 8192);
  float s = 0.0f, ss = 0.0f;
  for (int i = threadIdx.x; i < 2048; i += 256) {
    float4 v = p[i];
    s  += v.x + v.y + v.z + v.w;
    ss += v.x * v.x + v.y * v.y + v.z * v.z + v.w * v.w;
  }
  #pragma unroll
  for (int m = 1; m < 64; m <<= 1) { s += __shfl_xor(s, m); ss += __shfl_xor(ss, m); }
  __shared__ float rs[4], rss[4];
  const int wv = threadIdx.x >> 6;
  if ((threadIdx.x & 63) == 0) { rs[wv] = s; rss[wv] = ss; }
  __syncthreads();
  if (threadIdx.x == 0) {
    gpart[(blockIdx.x * 8 + blockIdx.y) * 2]     = rs[0] + rs[1] + rs[2] + rs[3];
    gpart[(blockIdx.x * 8 + blockIdx.y) * 2 + 1] = rss[0] + rss[1] + rss[2] + rss[3];
  }
}

// ---------------- GN apply (stage2 folded) + transpose to hT[8192][512] -----
__global__ __launch_bounds__(256) void gn_apply_kernel(const float* __restrict__ x,
                                                       const float* __restrict__ gnw,
                                                       const float* __restrict__ gnb,
                                                       const float* __restrict__ gpart,
                                                       u16* __restrict__ hT) {
  const int b = blockIdx.z, c0 = blockIdx.y * 64, hw0 = blockIdx.x * 64;
  const int t = threadIdx.x;
  __shared__ float tile[64][65];
  __shared__ float gmean[4], grstd[4];
  // stage2 fold: 4 threads reduce the 8 chunk-partials of their group
  if (t < 4) {
    const int g = b * 32 + (c0 >> 4) + t;
    float s = 0.0f, ss = 0.0f;
    #pragma unroll
    for (int cch = 0; cch < 8; ++cch) {
      s  += gpart[(g * 8 + cch) * 2];
      ss += gpart[(g * 8 + cch) * 2 + 1];
    }
    float mean = s * (1.0f / 65536.0f);
    float var  = fmaxf(ss * (1.0f / 65536.0f) - mean * mean, 0.0f);
    gmean[t] = mean;
    grstd[t] = rsqrtf(var + 1e-6f);
  }
  __syncthreads();
  {
    const int tx = t & 63, ty = t >> 6;  // ty 0..3
    #pragma unroll
    for (int i = 0; i < 16; ++i) {
      int cl = ty * 16 + i;
      int c = c0 + cl;
      float val = x[((size_t)(b * C_ + c)) * HW_ + hw0 + tx];
      tile[cl][tx] = (val - gmean[cl >> 4]) * grstd[cl >> 4] * gnw[c] + gnb[c];
    }
  }
  __syncthreads();
  {
    const int cx = (t & 31) * 2, ty = t >> 5;  // ty 0..7
    #pragma unroll
    for (int i = 0; i < 8; ++i) {
      int hwl = ty * 8 + i;
      unsigned pk = (unsigned)f2bf(tile[cx][hwl]) | ((unsigned)f2bf(tile[cx + 1][hwl]) << 16);
      *(unsigned*)&hT[((size_t)(b * HW_ + hw0 + hwl)) * C_ + c0 + cx] = pk;
    }
  }
}

// ---------------- generic bf16 A(MxK) @ B(NxK)^T GEMM, 64x64 tile -----------
// BIAS_N: bias indexed by n (else by m). RESID: fp32 out + residual add.
template<int BIAS_N, int RESID>
__global__ __launch_bounds__(256, 4) void gemm_abt(
    const u16* __restrict__ A, int lda,
    const u16* __restrict__ B, int ldb, long bz,
    const float* __restrict__ bias,
    const float* __restrict__ resid,
    void* __restrict__ Dp, int ldd, long dz, int K)
{
  B += (size_t)blockIdx.z * (size_t)bz;
  const int t = threadIdx.x;
  const int m0 = blockIdx.x * 64, n0 = blockIdx.y * 64;
  const int wv = t >> 6, l = t & 63, lr = l & 15, lq = l >> 4;
  const int ro = (wv >> 1) * 32, co = (wv & 1) * 32;
  __shared__ u16 As[64][72];
  __shared__ u16 Bs[64][72];
  f32x4 acc[2][2] = {};
  const int ldr_ = t >> 2;
  const int ldc_ = (t & 3) * 16;
  for (int k0 = 0; k0 < K; k0 += 64) {
    *(uint4*)&As[ldr_][ldc_]     = *(const uint4*)(A + (size_t)(m0 + ldr_) * lda + k0 + ldc_);
    *(uint4*)&As[ldr_][ldc_ + 8] = *(const uint4*)(A + (size_t)(m0 + ldr_) * lda + k0 + ldc_ + 8);
    *(uint4*)&Bs[ldr_][ldc_]     = *(const uint4*)(B + (size_t)(n0 + ldr_) * ldb + k0 + ldc_);
    *(uint4*)&Bs[ldr_][ldc_ + 8] = *(const uint4*)(B + (size_t)(n0 + ldr_) * ldb + k0 + ldc_ + 8);
    __syncthreads();
    #pragma unroll
    for (int kk = 0; kk < 64; kk += 32) {
      bf16x8 a0 = *(const bf16x8*)&As[ro + lr][kk + lq * 8];
      bf16x8 a1 = *(const bf16x8*)&As[ro + 16 + lr][kk + lq * 8];
      bf16x8 b0 = *(const bf16x8*)&Bs[co + lr][kk + lq * 8];
      bf16x8 b1 = *(const bf16x8*)&Bs[co + 16 + lr][kk + lq * 8];
      acc[0][0] = MFMA16(a0, b0, acc[0][0], 0, 0, 0);
      acc[0][1] = MFMA16(a0, b1, acc[0][1], 0, 0, 0);
      acc[1][0] = MFMA16(a1, b0, acc[1][0], 0, 0, 0);
      acc[1][1] = MFMA16(a1, b1, acc[1][1], 0, 0, 0);
    }
    __syncthreads();
  }
  #pragma unroll
  for (int rf = 0; rf < 2; ++rf) {
    #pragma unroll
    for (int cf = 0; cf < 2; ++cf) {
      const int n = n0 + co + cf * 16 + lr;
      const float bn = BIAS_N ? bias[n] : 0.0f;
      #pragma unroll
      for (int reg = 0; reg < 4; ++reg) {
        const int m = m0 + ro + rf * 16 + lq * 4 + reg;
        float val = acc[rf][cf][reg] + (BIAS_N ? bn : bias[m]);
        if (RESID) {
          float* D = (float*)Dp + (size_t)blockIdx.z * dz;
          const float* R = resid + (size_t)blockIdx.z * dz;
          size_t idx = (size_t)m * ldd + n;
          D[idx] = val + R[idx];
        } else {
          ((u16*)Dp)[(size_t)m * ldd + n] = f2bf(val);
        }
      }
    }
  }
}

// ---------------- fused Q+K GEMM, 128x128 tile (m97 structure) --------------
// A=hT [8192][512] (both batches as rows), B=wqkb [1024][512] (wq rows then
// wk rows), out qk[8192][1024]. Bias: n<512 -> qb[n], else kb[n-512].
// LDS XOR-swizzled (inverse-swizzled global src + swizzled ds_read).
__global__ __launch_bounds__(256, 2) void qkgemm_kernel(
    const u16* __restrict__ A, const u16* __restrict__ B,
    const float* __restrict__ qb, const float* __restrict__ kb,
    u16* __restrict__ qk)
{
  const int t = threadIdx.x;
  const int m0 = blockIdx.x * 128, n0 = blockIdx.y * 128;
  const int wv = t >> 6, l = t & 63, lr = l & 15, lq = l >> 4;
  const int wr = wv >> 1, wc = wv & 1;       // 2x2 waves of 64x64
  __shared__ u16 As[128][64];
  __shared__ u16 Bs[128][64];
  f32x4 acc[4][4] = {};
  for (int k0 = 0; k0 < 512; k0 += 64) {
    #pragma unroll
    for (int it = 0; it < 4; ++it) {
      const int ci = it * 256 + t;           // 1024 chunks of 16B
      const int row = ci >> 3;
      const int c8 = (((ci & 7) ^ (row & 7)) << 3);  // inverse-swizzled src octet
      gld_lds16(A + (size_t)(m0 + row) * 512 + k0 + c8, &As[0][0] + ci * 8);
      gld_lds16(B + (size_t)(n0 + row) * 512 + k0 + c8, &Bs[0][0] + ci * 8);
    }
    __syncthreads();
    #pragma unroll
    for (int kk = 0; kk < 64; kk += 32) {
      bf16x8 af[4], bf[4];
      #pragma unroll
      for (int fr = 0; fr < 4; ++fr)
        af[fr] = *(const bf16x8*)swz(&As[0][0], wr * 64 + fr * 16 + lr, kk + lq * 8, 64);
      #pragma unroll
      for (int fc = 0; fc < 4; ++fc)
        bf[fc] = *(const bf16x8*)swz(&Bs[0][0], wc * 64 + fc * 16 + lr, kk + lq * 8, 64);
      #pragma unroll
      for (int fr = 0; fr < 4; ++fr)
        #pragma unroll
        for (int fc = 0; fc < 4; ++fc)
          acc[fr][fc] = MFMA16(af[fr], bf[fc], acc[fr][fc], 0, 0, 0);
    }
    __syncthreads();
  }
  float bn[4];
  #pragma unroll
  for (int fc = 0; fc < 4; ++fc) {
    const int n = n0 + wc * 64 + fc * 16 + lr;
    bn[fc] = n < 512 ? qb[n] : kb[n - 512];
  }
  #pragma unroll
  for (int fr = 0; fr < 4; ++fr) {
    #pragma unroll
    for (int reg = 0; reg < 4; ++reg) {
      const int m = m0 + wr * 64 + fr * 16 + lq * 4 + reg;
      u16* orow = qk + (size_t)m * 1024 + n0 + wc * 64 + lr;
      #pragma unroll
      for (int fc = 0; fc < 4; ++fc)
        orow[fc * 16] = f2bf(acc[fr][fc][reg] + bn[fc]);
    }
  }
}

// ---------------- S-GEMM + exp + rowsum partials (m97 structure) ------------
// z = batch (big) or 0 (fallback; host pre-offsets). A,B = qk slices,
// lda/ldb = 1024 (q = cols 0..511, k = cols 512..1023). Tile 128x128, BK=64.
__global__ __launch_bounds__(256, 2) void sgemm_exp_kernel(
    const u16* __restrict__ A, const u16* __restrict__ B,
    u16* __restrict__ Pexp, float* __restrict__ rsp, long pz, int gi0base)
{
  const int z = blockIdx.z;
  A    += (size_t)z * (HW_ * 1024);
  B    += (size_t)z * (HW_ * 1024);
  Pexp += (size_t)z * pz;
  const int gi0 = gi0base + z * HW_;
  const int t = threadIdx.x;
  const int m0 = blockIdx.x * 128, n0 = blockIdx.y * 128;
  const int wv = t >> 6, l = t & 63, lr = l & 15, lq = l >> 4;
  const int wr = wv >> 1, wc = wv & 1;       // 2x2 waves of 64x64
  __shared__ u16 As[128][64];
  __shared__ u16 Bs[128][64];
  f32x4 acc[4][4] = {};
  for (int k0 = 0; k0 < 512; k0 += 64) {
    #pragma unroll
    for (int it = 0; it < 4; ++it) {
      const int ci = it * 256 + t;           // 1024 chunks of 16B
      const int row = ci >> 3;
      const int c8 = (((ci & 7) ^ (row & 7)) << 3);  // inverse-swizzled src octet
      gld_lds16(A + (size_t)(m0 + row) * 1024 + k0 + c8, &As[0][0] + ci * 8);
      gld_lds16(B + (size_t)(n0 + row) * 1024 + k0 + c8, &Bs[0][0] + ci * 8);
    }
    __syncthreads();
    #pragma unroll
    for (int kk = 0; kk < 64; kk += 32) {
      bf16x8 af[4], bf[4];
      #pragma unroll
      for (int fr = 0; fr < 4; ++fr)
        af[fr] = *(const bf16x8*)swz(&As[0][0], wr * 64 + fr * 16 + lr, kk + lq * 8, 64);
      #pragma unroll
      for (int fc = 0; fc < 4; ++fc)
        bf[fc] = *(const bf16x8*)swz(&Bs[0][0], wc * 64 + fc * 16 + lr, kk + lq * 8, 64);
      #pragma unroll
      for (int fr = 0; fr < 4; ++fr)
        #pragma unroll
        for (int fc = 0; fc < 4; ++fc)
          acc[fr][fc] = MFMA16(af[fr], bf[fc], acc[fr][fc], 0, 0, 0);
    }
    __syncthreads();
  }
  // epilogue: exp2(s*scale), rowsum partial over this wave's 64 cols, stores
  const float SCL2 = 0.06376774487989831f;   // log2(e)/sqrt(512)
  #pragma unroll
  for (int fr = 0; fr < 4; ++fr) {
    #pragma unroll
    for (int reg = 0; reg < 4; ++reg) {
      float rsum = 0.0f;
      const int row = m0 + wr * 64 + fr * 16 + lq * 4 + reg;
      u16* prow = Pexp + (size_t)row * 4096 + n0 + wc * 64 + lr;
      #pragma unroll
      for (int fc = 0; fc < 4; ++fc) {
        float p = exp2f(acc[fr][fc][reg] * SCL2);
        rsum += p;
        prow[fc * 16] = f2bf(p);
      }
      rsum += __shfl_xor(rsum, 1);
      rsum += __shfl_xor(rsum, 2);
      rsum += __shfl_xor(rsum, 4);
      rsum += __shfl_xor(rsum, 8);
      if (lr == 0)
        rsp[(size_t)(blockIdx.y * 2 + wc) * NTOK + gi0 + row] = rsum;
    }
  }
}

// ---------------- PV GEMM split-K, 128x128 tile (m97 2:1 MFMA:ds ratio) -----
// z encodes (split, batch): sp = z & (nsplit-1), bb = z >> logsplit.
// A=Pexp [4096][4096]; B=vm channel-major rows [512][tok]. BK=64.
// Op elem offset = sp*spstride + bb*2097152.
__global__ __launch_bounds__(256, 4) void pvgemm_splitk(
    const u16* __restrict__ A, const u16* __restrict__ B,
    u16* __restrict__ Op, long spstride, int logsplit)
{
  const int z = blockIdx.z;
  const int sp = z & ((1 << logsplit) - 1);
  const int bb = z >> logsplit;
  A  += (size_t)bb * PZ_;
  B  += (size_t)bb * HW_;
  Op += (size_t)sp * spstride + (size_t)bb * 2097152;
  const int t = threadIdx.x;
  const int m0 = blockIdx.x * 128, n0 = blockIdx.y * 128;
  const int wv = t >> 6, l = t & 63, lr = l & 15, lq = l >> 4;
  const int wr = wv >> 1, wc = wv & 1;       // 2x2 waves of 64x64
  __shared__ u16 As[128][64];
  __shared__ u16 Bs[128][64];
  f32x4 acc[4][4] = {};
  const int ksize = 4096 >> logsplit;
  const int kbeg = sp * ksize;
  for (int k0 = kbeg; k0 < kbeg + ksize; k0 += 64) {
    #pragma unroll
    for (int it = 0; it < 4; ++it) {
      const int ci = it * 256 + t;           // 1024 chunks of 16B per buffer
      const int row = ci >> 3;
      const int c8 = (((ci & 7) ^ (row & 7)) << 3);  // inverse-swizzled src octet
      gld_lds16(A + (size_t)(m0 + row) * 4096 + k0 + c8, &As[0][0] + ci * 8);
      gld_lds16(B + (size_t)(n0 + row) * NTOK + k0 + c8, &Bs[0][0] + ci * 8);
    }
    __syncthreads();
    #pragma unroll
    for (int kk = 0; kk < 64; kk += 32) {
      bf16x8 af[4], bf[4];
      #pragma unroll
      for (int fr = 0; fr < 4; ++fr)
        af[fr] = *(const bf16x8*)swz(&As[0][0], wr * 64 + fr * 16 + lr, kk + lq * 8, 64);
      #pragma unroll
      for (int fc = 0; fc < 4; ++fc)
        bf[fc] = *(const bf16x8*)swz(&Bs[0][0], wc * 64 + fc * 16 + lr, kk + lq * 8, 64);
      #pragma unroll
      for (int fr = 0; fr < 4; ++fr)
        #pragma unroll
        for (int fc = 0; fc < 4; ++fc)
          acc[fr][fc] = MFMA16(af[fr], bf[fc], acc[fr][fc], 0, 0, 0);
    }
    __syncthreads();
  }
  #pragma unroll
  for (int fr = 0; fr < 4; ++fr) {
    #pragma unroll
    for (int reg = 0; reg < 4; ++reg) {
      const int m = m0 + wr * 64 + fr * 16 + lq * 4 + reg;
      u16* orow = Op + (size_t)m * 512 + n0 + wc * 64 + lr;
      #pragma unroll
      for (int fc = 0; fc < 4; ++fc)
        orow[fc * 16] = f2bf(acc[fr][fc][reg]);
    }
  }
}

// ---------------- combine split-K partials + rowsum-normalize (folded) ------
// Block covers 2048 elems = 4 tokens. Wave w computes rinv for its token by
// reducing the 64 rowsum partials, then all threads combine nsplit partials.
__global__ __launch_bounds__(256) void combine_norm(const u16* __restrict__ Op,
                                                    const float* __restrict__ rsp,
                                                    u16* __restrict__ ao,
                                                    long spstride, int nsplit, int gi0) {
  const int t = threadIdx.x;
  __shared__ float rinvs[4];
  {
    const int tokl = t >> 6, jg = t & 63;
    float s = rsp[(size_t)jg * NTOK + gi0 + blockIdx.x * 4 + tokl];
    #pragma unroll
    for (int m = 1; m < 64; m <<= 1) s += __shfl_xor(s, m);
    if (jg == 0) rinvs[tokl] = 1.0f / s;
  }
  __syncthreads();
  const size_t idx8 = ((size_t)blockIdx.x * 256 + t) * 8;
  const float ri = rinvs[t >> 6];
  float v[8] = {};
  for (int s = 0; s < nsplit; ++s) {
    const u16* p = Op + (size_t)s * spstride + idx8;
    ushort4 a0 = *(const ushort4*)p;
    ushort4 a1 = *(const ushort4*)(p + 4);
    v[0] += bf2f(a0.x); v[1] += bf2f(a0.y); v[2] += bf2f(a0.z); v[3] += bf2f(a0.w);
    v[4] += bf2f(a1.x); v[5] += bf2f(a1.y); v[6] += bf2f(a1.z); v[7] += bf2f(a1.w);
  }
  ushort4 o0, o1;
  o0.x = f2bf(v[0] * ri); o0.y = f2bf(v[1] * ri);
  o0.z = f2bf(v[2] * ri); o0.w = f2bf(v[3] * ri);
  o1.x = f2bf(v[4] * ri); o1.y = f2bf(v[5] * ri);
  o1.z = f2bf(v[6] * ri); o1.w = f2bf(v[7] * ri);
  *(ushort4*)(ao + idx8)     = o0;
  *(ushort4*)(ao + idx8 + 4) = o1;
}

extern "C" void kernel_launch(void* const* d_in, const int* in_sizes, int n_in,
                              void* d_out, int out_size, void* d_ws, size_t ws_size,
                              hipStream_t stream) {
  const float* x   = (const float*)d_in[0];
  const float* gnw = (const float*)d_in[1];
  const float* gnb = (const float*)d_in[2];
  const float* qw  = (const float*)d_in[3];
  const float* qb  = (const float*)d_in[4];
  const float* kw  = (const float*)d_in[5];
  const float* kb  = (const float*)d_in[6];
  const float* vw  = (const float*)d_in[7];
  const float* vb  = (const float*)d_in[8];
  const float* pw  = (const float*)d_in[9];
  const float* pb  = (const float*)d_in[10];

  // common prefix layout (both modes)
  char* ws = (char*)d_ws;
  u16*   wqb   = (u16*)(ws + 0);             // wq then wk rows: [1024][512] bf16
  u16*   wkb   = wqb + 262144;
  u16*   wvb   = wkb + 262144;
  u16*   wpb   = wvb + 262144;
  float* rsp   = (float*)(ws + 2130432);     // [64][8192] f32 (2MB)
  float* gpart = rsp;                        // gn partials alias rsp (pre-sgemm)
  u16*   hT    = (u16*)(ws + 4227584);       // [8192][512] bf16 (8MB), dead after v-GEMM
  u16*   ao    = hT;                         // reuses hT region: [2][4096][512] bf16
  u16*   qk    = (u16*)(ws + 12616192);      // [8192][1024] bf16 (16MB, q|k per row)
  u16*   vm    = (u16*)(ws + 29393408);      // [512][8192] bf16

  // big mode (ws >= ~138.5MB): both-batch Pexp + 4-way split-K Op partials
  const bool big = ws_size >= 138445312ULL;
  u16* OpB   = (u16*)(ws + 37782016);        // [4][2][4096][512] bf16 (33.5MB)
  u16* PexpB = (u16*)(ws + 71336448);        // [2][4096][4096] bf16 (67MB)
  // fallback (ws >= 77.66MB proven): single-batch Pexp, Op strided over qk
  u16* PexpS = (u16*)(ws + 37782016);        // [4096][4096] bf16 (33.5MB)

  wcast_kernel<<<1024, 256, 0, stream>>>(qw, kw, vw, pw, wqb);
  gn_stats1_kernel<<<dim3(64, 8), 256, 0, stream>>>(x, gpart);
  gn_apply_kernel<<<dim3(64, 8, 2), 256, 0, stream>>>(x, gnw, gnb, gpart, hT);
  // fused q+k: one 128^2-tile GEMM, N=1024, both batches as rows
  qkgemm_kernel<<<dim3(64, 8), 256, 0, stream>>>(hT, wqb, qb, kb, qk);
  // v: channel-major, bias per-m
  gemm_abt<0, 0><<<dim3(8, 128), 256, 0, stream>>>(wvb, 512, hT, 512, 0, vb, nullptr, vm, 8192, 0, 512);

  if (big) {
    sgemm_exp_kernel<<<dim3(32, 32, 2), 256, 0, stream>>>(qk, qk + 512, PexpB, rsp, PZ_, 0);
    pvgemm_splitk<<<dim3(32, 4, 8), 256, 0, stream>>>(PexpB, vm, OpB, 4194304L, 2);
    combine_norm<<<2048, 256, 0, stream>>>(OpB, rsp, ao, 4194304L, 4, 0);
  } else {
    for (int b = 0; b < 2; ++b) {
      const u16* qkb = qk + (size_t)b * HW_ * 1024;
      sgemm_exp_kernel<<<dim3(32, 32, 1), 256, 0, stream>>>(qkb, qkb + 512, PexpS, rsp, 0L, b * HW_);
      // Op = 2 splits strided over the dead qk b0 region (2x 4MB)
      pvgemm_splitk<<<dim3(32, 4, 2), 256, 0, stream>>>(PexpS, vm + (size_t)b * HW_, qk, 2097152L, 1);
      combine_norm<<<1024, 256, 0, stream>>>(qk, rsp, ao + (size_t)b * HW_ * C_, 2097152L, 2, b * HW_);
    }
  }
  // proj + bias + residual, fp32 out, per-batch via blockIdx.z
  gemm_abt<0, 1><<<dim3(8, 64, 2), 256, 0, stream>>>(wpb, 512, ao, 512, 2097152L, pb, x, d_out, 4096, 2097152L, 512);
}